// Round 1
// baseline (1496.521 us; speedup 1.0000x reference)
//
#include <hip/hip_runtime.h>
#include <hip/hip_bf16.h>
#include <stdint.h>

#define N_NODES 100000
constexpr float BN_EPS = 1e-5f;

// ---------------- edge-index dtype detection & normalization ----------------
// If ei is int64 (little-endian), every odd 32-bit word is 0 (values < 1e5).
// If int32, odd words are random indices — virtually certainly nonzero.
__global__ void k_detect_idx(const unsigned int* __restrict__ w, int nwords,
                             int* __restrict__ flag) {
    __shared__ int s;
    if (threadIdx.x == 0) s = 0;
    __syncthreads();
    for (int i = 1 + 2 * (int)threadIdx.x; i < nwords; i += 2 * (int)blockDim.x)
        if (w[i] != 0u) s = 1;
    __syncthreads();
    if (threadIdx.x == 0) *flag = s;   // 1 => int32, 0 => int64
}

__global__ void k_convert_idx(const unsigned int* __restrict__ w, int n,
                              const int* __restrict__ flag, int* __restrict__ out) {
    int i = blockIdx.x * blockDim.x + threadIdx.x;
    if (i < n) out[i] = (int)((*flag) ? w[i] : w[2 * i]);
}

// ---------------- fp32 tiled GEMM: C[M,Ncol] = A[M,K] @ W[K,Ncol] ----------
// 64x64 tile / block, 256 threads, 4x4 micro-tile, BK=64 LDS staging.
// sA stored transposed [k][row] with pitch 68 (float4-aligned, 8-way store
// conflict only on the staging writes; inner-loop reads are k-uniform =>
// conflict-free).
template <int K>
__global__ __launch_bounds__(256) void k_gemm(const float* __restrict__ A,
                                              const float* __restrict__ W,
                                              float* __restrict__ C,
                                              int M, int Ncol) {
    constexpr int BK = 64;
    constexpr int PITCH = 68;
    __shared__ float sA[BK * PITCH];  // 17.0 KB
    __shared__ float sB[BK * 64];     // 16.0 KB
    const int row0 = blockIdx.x * 64;
    const int col0 = blockIdx.y * 64;
    const int tid = threadIdx.x;
    const int tc = (tid & 15) * 4;
    const int tr = (tid >> 4) * 4;

    float acc[4][4] = {};

    for (int k0 = 0; k0 < K; k0 += BK) {
        if (k0) __syncthreads();
        // stage A tile (64 rows x BK), transposed into sA[k][r]
        #pragma unroll
        for (int idx = tid; idx < 64 * BK; idx += 256) {
            int r = idx >> 6, k = idx & 63;
            int gr = row0 + r;
            sA[k * PITCH + r] = (gr < M) ? A[(size_t)gr * K + k0 + k] : 0.f;
        }
        // stage B tile (BK x 64), row-major
        #pragma unroll
        for (int idx = tid; idx < BK * 64; idx += 256) {
            int k = idx >> 6, c = idx & 63;
            sB[idx] = W[(size_t)(k0 + k) * Ncol + col0 + c];
        }
        __syncthreads();

        #pragma unroll
        for (int k = 0; k < BK; ++k) {
            const float4 a4 = *(const float4*)(sA + k * PITCH + tr);
            const float4 b4 = *(const float4*)(sB + (k << 6) + tc);
            float av[4] = {a4.x, a4.y, a4.z, a4.w};
            float bv[4] = {b4.x, b4.y, b4.z, b4.w};
            #pragma unroll
            for (int i = 0; i < 4; ++i)
                #pragma unroll
                for (int j = 0; j < 4; ++j)
                    acc[i][j] = fmaf(av[i], bv[j], acc[i][j]);
        }
    }

    #pragma unroll
    for (int i = 0; i < 4; ++i) {
        int gr = row0 + tr + i;
        if (gr < M) {
            float4 o = make_float4(acc[i][0], acc[i][1], acc[i][2], acc[i][3]);
            *(float4*)(C + (size_t)gr * Ncol + col0 + tc) = o;
        }
    }
}

// ---------------- degree count ----------------
__global__ void k_degree(const int* __restrict__ dst, float* __restrict__ cnt, int E) {
    int e = blockIdx.x * blockDim.x + threadIdx.x;
    if (e < E) atomicAdd(&cnt[dst[e]], 1.0f);
}

// ---------------- scatter-add of transformed features ----------------
// one thread per (edge, feature)
template <int LOGF>
__global__ void k_scatter(const float* __restrict__ feat, const int* __restrict__ src,
                          const int* __restrict__ dst, float* __restrict__ agg,
                          long long total) {
    long long i = (long long)blockIdx.x * blockDim.x + threadIdx.x;
    if (i >= total) return;
    int e = (int)(i >> LOGF);
    int f = (int)(i & ((1 << LOGF) - 1));
    int s = src[e], d = dst[e];
    atomicAdd(&agg[((size_t)d << LOGF) + f], feat[((size_t)s << LOGF) + f]);
}

// ---------------- node update: mean + bias + lin_r + BN + ReLU -------------
template <int LOGF>
__global__ void k_node(const float* __restrict__ agg, const float* __restrict__ cnt,
                       const float* __restrict__ lin, const float* __restrict__ b,
                       const float* __restrict__ g, const float* __restrict__ be,
                       const float* __restrict__ m, const float* __restrict__ v,
                       float* __restrict__ out, int total) {
    int i = blockIdx.x * blockDim.x + threadIdx.x;
    if (i >= total) return;
    int f = i & ((1 << LOGF) - 1);
    int n = i >> LOGF;
    float c = fmaxf(cnt[n], 1.0f);
    float xv = agg[i] / c + b[f] + lin[i];
    float y = (xv - m[f]) * (g[f] * rsqrtf(v[f] + BN_EPS)) + be[f];
    out[i] = fmaxf(y, 0.0f);
}

// ---------------- head: out[M,10] = h2[M,64] @ Wh[64,10] + bh --------------
__global__ __launch_bounds__(256) void k_head(const float* __restrict__ h2,
                                              const float* __restrict__ Wh,
                                              const float* __restrict__ bh,
                                              float* __restrict__ out, int M) {
    __shared__ float sW[64 * 10];
    __shared__ float sb[10];
    for (int i = threadIdx.x; i < 640; i += 256) sW[i] = Wh[i];
    if (threadIdx.x < 10) sb[threadIdx.x] = bh[threadIdx.x];
    __syncthreads();
    int n = blockIdx.x * blockDim.x + threadIdx.x;
    if (n >= M) return;
    float acc[10];
    #pragma unroll
    for (int c = 0; c < 10; ++c) acc[c] = sb[c];
    const float* hr = h2 + (size_t)n * 64;
    #pragma unroll
    for (int k = 0; k < 64; ++k) {
        float hv = hr[k];
        #pragma unroll
        for (int c = 0; c < 10; ++c) acc[c] = fmaf(hv, sW[k * 10 + c], acc[c]);
    }
    #pragma unroll
    for (int c = 0; c < 10; ++c) out[(size_t)n * 10 + c] = acc[c];
}

// ---------------------------------------------------------------------------
extern "C" void kernel_launch(void* const* d_in, const int* in_sizes, int n_in,
                              void* d_out, int out_size, void* d_ws, size_t ws_size,
                              hipStream_t stream) {
    const float* x   = (const float*)d_in[0];
    const void*  ei  = d_in[1];
    const float* W1l = (const float*)d_in[2];
    const float* b1l = (const float*)d_in[3];
    const float* W1r = (const float*)d_in[4];
    const float* g1  = (const float*)d_in[5];
    const float* be1 = (const float*)d_in[6];
    const float* m1  = (const float*)d_in[7];
    const float* v1  = (const float*)d_in[8];
    const float* W2l = (const float*)d_in[9];
    const float* b2l = (const float*)d_in[10];
    const float* W2r = (const float*)d_in[11];
    const float* g2  = (const float*)d_in[12];
    const float* be2 = (const float*)d_in[13];
    const float* m2  = (const float*)d_in[14];
    const float* v2  = (const float*)d_in[15];
    const float* Wh  = (const float*)d_in[16];
    const float* bh  = (const float*)d_in[17];
    float* out = (float*)d_out;

    const int N = N_NODES;
    const int E = in_sizes[1] / 2;

    // -------- workspace layout (reused aggressively) --------
    char* p = (char*)d_ws;
    int* flag   = (int*)p;              p += 256;
    int* idx32  = (int*)p;              p += (size_t)2 * E * 4;   // [src | dst]
    float* xl   = (float*)p;            p += (size_t)N * 128 * 4;
    float* xr   = (float*)p;            p += (size_t)N * 128 * 4;
    float* agg1 = (float*)p;            p += (size_t)N * 128 * 4;
    float* cnt  = (float*)p;            p += (size_t)N * 4;
    int* src32 = idx32;
    int* dst32 = idx32 + E;
    // reuse: dead buffers recycled
    float* h    = xl;                    // [N,128] layer-1 output
    float* t2l  = xr;                    // [N,64]
    float* t2r  = xr + (size_t)N * 64;   // [N,64]
    float* agg2 = agg1;                  // [N,64]
    float* h2   = agg1 + (size_t)N * 64; // [N,64]

    dim3 blk(256);

    // -------- normalize edge indices to int32 --------
    int nwords = 4 * E < 8192 ? 4 * E : 8192;
    k_detect_idx<<<dim3(1), blk, 0, stream>>>((const unsigned int*)ei, nwords, flag);
    {
        int n2 = 2 * E;
        k_convert_idx<<<dim3((n2 + 255) / 256), blk, 0, stream>>>(
            (const unsigned int*)ei, n2, flag, idx32);
    }

    hipMemsetAsync(agg1, 0, (size_t)N * 128 * 4, stream);
    hipMemsetAsync(cnt, 0, (size_t)N * 4, stream);

    // -------- layer 1: transform-first, then scatter-mean --------
    dim3 gemm1_grid((N + 63) / 64, 2);
    k_gemm<128><<<gemm1_grid, blk, 0, stream>>>(x, W1l, xl, N, 128);
    k_gemm<128><<<gemm1_grid, blk, 0, stream>>>(x, W1r, xr, N, 128);
    k_degree<<<dim3((E + 255) / 256), blk, 0, stream>>>(dst32, cnt, E);
    {
        long long total = (long long)E * 128;
        k_scatter<7><<<dim3((unsigned)((total + 255) / 256)), blk, 0, stream>>>(
            xl, src32, dst32, agg1, total);
    }
    k_node<7><<<dim3((N * 128 + 255) / 256), blk, 0, stream>>>(
        agg1, cnt, xr, b1l, g1, be1, m1, v1, h, N * 128);

    // -------- layer 2 --------
    dim3 gemm2_grid((N + 63) / 64, 1);
    k_gemm<128><<<gemm2_grid, blk, 0, stream>>>(h, W2l, t2l, N, 64);
    k_gemm<128><<<gemm2_grid, blk, 0, stream>>>(h, W2r, t2r, N, 64);
    hipMemsetAsync(agg2, 0, (size_t)N * 64 * 4, stream);
    {
        long long total = (long long)E * 64;
        k_scatter<6><<<dim3((unsigned)((total + 255) / 256)), blk, 0, stream>>>(
            t2l, src32, dst32, agg2, total);
    }
    k_node<6><<<dim3((N * 64 + 255) / 256), blk, 0, stream>>>(
        agg2, cnt, t2r, b2l, g2, be2, m2, v2, h2, N * 64);

    // -------- head --------
    k_head<<<dim3((N + 255) / 256), blk, 0, stream>>>(h2, Wh, bh, out, N);
}

// Round 2
// 811.647 us; speedup vs baseline: 1.8438x; 1.8438x over previous
//
#include <hip/hip_runtime.h>
#include <hip/hip_bf16.h>
#include <stdint.h>

#define N_NODES 100000
constexpr float BN_EPS = 1e-5f;

// ---------------- edge-index dtype detection & normalization ----------------
__global__ void k_detect_idx(const unsigned int* __restrict__ w, int nwords,
                             int* __restrict__ flag) {
    __shared__ int s;
    if (threadIdx.x == 0) s = 0;
    __syncthreads();
    for (int i = 1 + 2 * (int)threadIdx.x; i < nwords; i += 2 * (int)blockDim.x)
        if (w[i] != 0u) s = 1;
    __syncthreads();
    if (threadIdx.x == 0) *flag = s;   // 1 => int32, 0 => int64
}

__global__ void k_convert_idx(const unsigned int* __restrict__ w, int n,
                              const int* __restrict__ flag, int* __restrict__ out) {
    int i = blockIdx.x * blockDim.x + threadIdx.x;
    if (i < n) out[i] = (int)((*flag) ? w[i] : w[2 * i]);
}

// ---------------- fp32 tiled GEMM: C[M,Ncol] = A[M,K] @ W[K,Ncol] ----------
template <int K>
__global__ __launch_bounds__(256) void k_gemm(const float* __restrict__ A,
                                              const float* __restrict__ W,
                                              float* __restrict__ C,
                                              int M, int Ncol) {
    constexpr int BK = 64;
    constexpr int PITCH = 68;
    __shared__ float sA[BK * PITCH];
    __shared__ float sB[BK * 64];
    const int row0 = blockIdx.x * 64;
    const int col0 = blockIdx.y * 64;
    const int tid = threadIdx.x;
    const int tc = (tid & 15) * 4;
    const int tr = (tid >> 4) * 4;

    float acc[4][4] = {};

    for (int k0 = 0; k0 < K; k0 += BK) {
        if (k0) __syncthreads();
        #pragma unroll
        for (int idx = tid; idx < 64 * BK; idx += 256) {
            int r = idx >> 6, k = idx & 63;
            int gr = row0 + r;
            sA[k * PITCH + r] = (gr < M) ? A[(size_t)gr * K + k0 + k] : 0.f;
        }
        #pragma unroll
        for (int idx = tid; idx < BK * 64; idx += 256) {
            int k = idx >> 6, c = idx & 63;
            sB[idx] = W[(size_t)(k0 + k) * Ncol + col0 + c];
        }
        __syncthreads();

        #pragma unroll
        for (int k = 0; k < BK; ++k) {
            const float4 a4 = *(const float4*)(sA + k * PITCH + tr);
            const float4 b4 = *(const float4*)(sB + (k << 6) + tc);
            float av[4] = {a4.x, a4.y, a4.z, a4.w};
            float bv[4] = {b4.x, b4.y, b4.z, b4.w};
            #pragma unroll
            for (int i = 0; i < 4; ++i)
                #pragma unroll
                for (int j = 0; j < 4; ++j)
                    acc[i][j] = fmaf(av[i], bv[j], acc[i][j]);
        }
    }

    #pragma unroll
    for (int i = 0; i < 4; ++i) {
        int gr = row0 + tr + i;
        if (gr < M) {
            float4 o = make_float4(acc[i][0], acc[i][1], acc[i][2], acc[i][3]);
            *(float4*)(C + (size_t)gr * Ncol + col0 + tc) = o;
        }
    }
}

// ---------------- CSR build ----------------
__global__ void k_deg(const int* __restrict__ dst, int* __restrict__ deg, int E) {
    int e = blockIdx.x * blockDim.x + threadIdx.x;
    if (e < E) atomicAdd(&deg[dst[e]], 1);
}

// block-level exclusive scan (256 elems/block), emit block sums
__global__ __launch_bounds__(256) void k_scan1(const int* __restrict__ deg,
                                               int* __restrict__ offs,
                                               int* __restrict__ bsum, int n) {
    __shared__ int s[256];
    int t = threadIdx.x;
    int i = blockIdx.x * 256 + t;
    int v = (i < n) ? deg[i] : 0;
    s[t] = v;
    __syncthreads();
    for (int off = 1; off < 256; off <<= 1) {
        int add = (t >= off) ? s[t - off] : 0;
        __syncthreads();
        s[t] += add;
        __syncthreads();
    }
    if (i < n) offs[i] = s[t] - v;      // exclusive
    if (t == 255) bsum[blockIdx.x] = s[255];
}

// single-block scan of block sums (exclusive)
__global__ __launch_bounds__(256) void k_scan2(int* __restrict__ bsum, int nb) {
    __shared__ int s[256];
    __shared__ int carry;
    int t = threadIdx.x;
    if (t == 0) carry = 0;
    __syncthreads();
    for (int base = 0; base < nb; base += 256) {
        int i = base + t;
        int v = (i < nb) ? bsum[i] : 0;
        s[t] = v;
        __syncthreads();
        for (int off = 1; off < 256; off <<= 1) {
            int add = (t >= off) ? s[t - off] : 0;
            __syncthreads();
            s[t] += add;
            __syncthreads();
        }
        if (i < nb) bsum[i] = s[t] - v + carry;
        __syncthreads();
        if (t == 0) carry += s[255];
        __syncthreads();
    }
}

__global__ void k_scan3(int* __restrict__ offs, const int* __restrict__ bsum,
                        int n, int E) {
    int i = blockIdx.x * blockDim.x + threadIdx.x;
    if (i < n) offs[i] += bsum[i >> 8];
    if (i == 0) offs[n] = E;
}

// bin edges into CSR: csr[pos] = src, pos = offs[dst] + fill[dst]++
__global__ void k_bin(const int* __restrict__ src, const int* __restrict__ dst,
                      const int* __restrict__ offs, int* __restrict__ fill,
                      int* __restrict__ csr, int E) {
    int e = blockIdx.x * blockDim.x + threadIdx.x;
    if (e >= E) return;
    int d = dst[e];
    int pos = offs[d] + atomicAdd(&fill[d], 1);
    csr[pos] = src[e];
}

// ---------------- fused gather-aggregate + mean + lin_r + BN + ReLU --------
// one wave (64 lanes) per node; F=128: float2/lane, F=64: float/lane
template <int LOGF>
__global__ __launch_bounds__(256) void k_agg(const float* __restrict__ xl,
                                             const float* __restrict__ lin,
                                             const int* __restrict__ csr,
                                             const int* __restrict__ offs,
                                             const float* __restrict__ b,
                                             const float* __restrict__ g,
                                             const float* __restrict__ be,
                                             const float* __restrict__ m,
                                             const float* __restrict__ v,
                                             float* __restrict__ out, int N) {
    constexpr int F = 1 << LOGF;
    int node = blockIdx.x * 4 + (threadIdx.x >> 6);
    if (node >= N) return;
    int lane = threadIdx.x & 63;
    int beg = offs[node], end = offs[node + 1];
    float c = fmaxf((float)(end - beg), 1.0f);
    float inv = 1.0f / c;

    if constexpr (F == 128) {
        float sx = 0.f, sy = 0.f;
        const float2* base = (const float2*)xl;
        for (int e = beg; e < end; ++e) {
            int sidx = csr[e];
            float2 t = base[(size_t)sidx * 64 + lane];
            sx += t.x; sy += t.y;
        }
        int f0 = lane * 2;
        size_t o = (size_t)node * 128 + f0;
        float2 l2 = *(const float2*)(lin + o);
        float y0 = ((sx * inv + b[f0]     + l2.x) - m[f0])     * (g[f0]     * rsqrtf(v[f0]     + BN_EPS)) + be[f0];
        float y1 = ((sy * inv + b[f0 + 1] + l2.y) - m[f0 + 1]) * (g[f0 + 1] * rsqrtf(v[f0 + 1] + BN_EPS)) + be[f0 + 1];
        *(float2*)(out + o) = make_float2(fmaxf(y0, 0.f), fmaxf(y1, 0.f));
    } else {
        float s = 0.f;
        for (int e = beg; e < end; ++e)
            s += xl[(size_t)csr[e] * 64 + lane];
        size_t o = (size_t)node * 64 + lane;
        float y = ((s * inv + b[lane] + lin[o]) - m[lane]) * (g[lane] * rsqrtf(v[lane] + BN_EPS)) + be[lane];
        out[o] = fmaxf(y, 0.f);
    }
}

// ---------------- head: out[M,10] = h2[M,64] @ Wh[64,10] + bh --------------
__global__ __launch_bounds__(256) void k_head(const float* __restrict__ h2,
                                              const float* __restrict__ Wh,
                                              const float* __restrict__ bh,
                                              float* __restrict__ out, int M) {
    __shared__ float sW[64 * 10];
    __shared__ float sb[10];
    for (int i = threadIdx.x; i < 640; i += 256) sW[i] = Wh[i];
    if (threadIdx.x < 10) sb[threadIdx.x] = bh[threadIdx.x];
    __syncthreads();
    int n = blockIdx.x * blockDim.x + threadIdx.x;
    if (n >= M) return;
    float acc[10];
    #pragma unroll
    for (int c = 0; c < 10; ++c) acc[c] = sb[c];
    const float* hr = h2 + (size_t)n * 64;
    #pragma unroll
    for (int k = 0; k < 64; ++k) {
        float hv = hr[k];
        #pragma unroll
        for (int c = 0; c < 10; ++c) acc[c] = fmaf(hv, sW[k * 10 + c], acc[c]);
    }
    #pragma unroll
    for (int c = 0; c < 10; ++c) out[(size_t)n * 10 + c] = acc[c];
}

// ---------------------------------------------------------------------------
static inline size_t align256(size_t x) { return (x + 255) & ~(size_t)255; }

extern "C" void kernel_launch(void* const* d_in, const int* in_sizes, int n_in,
                              void* d_out, int out_size, void* d_ws, size_t ws_size,
                              hipStream_t stream) {
    const float* x   = (const float*)d_in[0];
    const void*  ei  = d_in[1];
    const float* W1l = (const float*)d_in[2];
    const float* b1l = (const float*)d_in[3];
    const float* W1r = (const float*)d_in[4];
    const float* g1  = (const float*)d_in[5];
    const float* be1 = (const float*)d_in[6];
    const float* m1  = (const float*)d_in[7];
    const float* v1  = (const float*)d_in[8];
    const float* W2l = (const float*)d_in[9];
    const float* b2l = (const float*)d_in[10];
    const float* W2r = (const float*)d_in[11];
    const float* g2  = (const float*)d_in[12];
    const float* be2 = (const float*)d_in[13];
    const float* m2  = (const float*)d_in[14];
    const float* v2  = (const float*)d_in[15];
    const float* Wh  = (const float*)d_in[16];
    const float* bh  = (const float*)d_in[17];
    float* out = (float*)d_out;

    const int N = N_NODES;
    const int E = in_sizes[1] / 2;
    const int NB = (N + 255) / 256;

    // -------- workspace layout --------
    char* p = (char*)d_ws;
    int* flag  = (int*)p;  p += 256;
    int* idx32 = (int*)p;  p += align256((size_t)2 * E * 4);
    int* csr   = (int*)p;  p += align256((size_t)E * 4);
    int* offs  = (int*)p;  p += align256((size_t)(N + 1) * 4);
    int* deg   = (int*)p;  p += align256((size_t)N * 4);
    int* fill  = (int*)p;  p += align256((size_t)N * 4);
    int* bsum  = (int*)p;  p += 4096;
    float* xl  = (float*)p; p += (size_t)N * 128 * 4;
    float* xr  = (float*)p; p += (size_t)N * 128 * 4;
    float* h   = (float*)p; p += (size_t)N * 128 * 4;
    int* src32 = idx32;
    int* dst32 = idx32 + E;
    // layer-2 reuse of dead buffers
    float* t2l = xl;                     // [N,64]
    float* t2r = xr;                     // [N,64]
    float* h2  = h;                      // [N,64] (h dead once t2l/t2r built)

    dim3 blk(256);

    // -------- normalize edge indices to int32 --------
    int nwords = 4 * E < 8192 ? 4 * E : 8192;
    k_detect_idx<<<dim3(1), blk, 0, stream>>>((const unsigned int*)ei, nwords, flag);
    {
        int n2 = 2 * E;
        k_convert_idx<<<dim3((n2 + 255) / 256), blk, 0, stream>>>(
            (const unsigned int*)ei, n2, flag, idx32);
    }

    // -------- CSR build --------
    hipMemsetAsync(deg, 0, (size_t)N * 4, stream);
    hipMemsetAsync(fill, 0, (size_t)N * 4, stream);
    k_deg<<<dim3((E + 255) / 256), blk, 0, stream>>>(dst32, deg, E);
    k_scan1<<<dim3(NB), blk, 0, stream>>>(deg, offs, bsum, N);
    k_scan2<<<dim3(1), blk, 0, stream>>>(bsum, NB);
    k_scan3<<<dim3(NB), blk, 0, stream>>>(offs, bsum, N, E);
    k_bin<<<dim3((E + 255) / 256), blk, 0, stream>>>(src32, dst32, offs, fill, csr, E);

    // -------- layer 1 --------
    dim3 gemm1_grid((N + 63) / 64, 2);
    k_gemm<128><<<gemm1_grid, blk, 0, stream>>>(x, W1l, xl, N, 128);
    k_gemm<128><<<gemm1_grid, blk, 0, stream>>>(x, W1r, xr, N, 128);
    k_agg<7><<<dim3((N + 3) / 4), blk, 0, stream>>>(
        xl, xr, csr, offs, b1l, g1, be1, m1, v1, h, N);

    // -------- layer 2 --------
    dim3 gemm2_grid((N + 63) / 64, 1);
    k_gemm<128><<<gemm2_grid, blk, 0, stream>>>(h, W2l, t2l, N, 64);
    k_gemm<128><<<gemm2_grid, blk, 0, stream>>>(h, W2r, t2r, N, 64);
    k_agg<6><<<dim3((N + 3) / 4), blk, 0, stream>>>(
        t2l, t2r, csr, offs, b2l, g2, be2, m2, v2, h2, N);

    // -------- head --------
    k_head<<<dim3((N + 255) / 256), blk, 0, stream>>>(h2, Wh, bh, out, N);
}

// Round 3
// 485.893 us; speedup vs baseline: 3.0799x; 1.6704x over previous
//
#include <hip/hip_runtime.h>
#include <hip/hip_bf16.h>
#include <stdint.h>

#define N_NODES 100000
constexpr float BN_EPS = 1e-5f;

typedef __bf16 bf16x8 __attribute__((ext_vector_type(8)));
typedef float f32x4 __attribute__((ext_vector_type(4)));

// ---------------- edge-index dtype detection & normalization ----------------
__global__ void k_detect_idx(const unsigned int* __restrict__ w, int nwords,
                             int* __restrict__ flag) {
    __shared__ int s;
    if (threadIdx.x == 0) s = 0;
    __syncthreads();
    for (int i = 1 + 2 * (int)threadIdx.x; i < nwords; i += 2 * (int)blockDim.x)
        if (w[i] != 0u) s = 1;
    __syncthreads();
    if (threadIdx.x == 0) *flag = s;   // 1 => int32, 0 => int64
}

__global__ void k_convert_idx(const unsigned int* __restrict__ w, int n,
                              const int* __restrict__ flag, int* __restrict__ out) {
    int i = blockIdx.x * blockDim.x + threadIdx.x;
    if (i < n) out[i] = (int)((*flag) ? w[i] : w[2 * i]);
}

// ---------------- W prep: split fp32 W into bf16 hi/lo, transposed ----------
// Wt[c][k] for c in [0, 2*halfN), col-concat of Wl|Wr ([K][halfN] each)
__global__ void k_wprep(const float* __restrict__ Wl, const float* __restrict__ Wr,
                        int K, int halfN, __bf16* __restrict__ Wthi,
                        __bf16* __restrict__ Wtlo) {
    int idx = blockIdx.x * 256 + threadIdx.x;
    int total = 2 * halfN * K;
    if (idx >= total) return;
    int c = idx / K, k = idx - c * K;
    const float* W = (c < halfN) ? Wl : Wr;
    int cc = (c < halfN) ? c : c - halfN;
    float v = W[(size_t)k * halfN + cc];
    __bf16 h = (__bf16)v;
    Wthi[idx] = h;
    Wtlo[idx] = (__bf16)(v - (float)h);
}

// ---------------- bf16x3 MFMA GEMM: C = A[f32] @ W (exact-ish) ------------
// Block = 4 waves, each wave owns 32 rows; covers NCS*32 cols.
// A-frags loaded direct from global (f32) + in-register hi/lo split.
// B-frags from pre-split, pre-transposed Wt (L2-resident, 16B loads).
// Output: cols [0,SPLITC) -> Cl (bf16, stride SPLITC); rest -> Cr (f32).
template <int K, int NCS, int SPLITC>
__global__ __launch_bounds__(256) void k_mfma(const float* __restrict__ A,
                                              const __bf16* __restrict__ Wthi,
                                              const __bf16* __restrict__ Wtlo,
                                              __bf16* __restrict__ Cl,
                                              float* __restrict__ Cr,
                                              int M) {
    const int lane = threadIdx.x & 63;
    const int wave = threadIdx.x >> 6;
    const int row0 = blockIdx.x * 128 + wave * 32;
    const int rlo = lane & 15;
    const int rhi = lane >> 4;            // 0..3

    f32x4 acc[NCS][2][2] = {};

    for (int k0 = 0; k0 < K; k0 += 32) {
        bf16x8 ahi[2], alo[2];
        #pragma unroll
        for (int wr = 0; wr < 2; ++wr) {
            int row = row0 + wr * 16 + rlo;
            row = row < M ? row : M - 1;
            const float* ap = A + (size_t)row * K + k0 + rhi * 8;
            float4 v0 = *(const float4*)ap;
            float4 v1 = *(const float4*)(ap + 4);
            float vv[8] = {v0.x, v0.y, v0.z, v0.w, v1.x, v1.y, v1.z, v1.w};
            #pragma unroll
            for (int i = 0; i < 8; ++i) {
                __bf16 h = (__bf16)vv[i];
                ahi[wr][i] = h;
                alo[wr][i] = (__bf16)(vv[i] - (float)h);
            }
        }
        #pragma unroll
        for (int cs = 0; cs < NCS; ++cs) {
            #pragma unroll
            for (int cf = 0; cf < 2; ++cf) {
                int c = cs * 32 + cf * 16 + rlo;
                size_t boff = (size_t)c * K + k0 + rhi * 8;
                bf16x8 bhi = *(const bf16x8*)(Wthi + boff);
                bf16x8 blo = *(const bf16x8*)(Wtlo + boff);
                #pragma unroll
                for (int wr = 0; wr < 2; ++wr) {
                    f32x4 a = acc[cs][wr][cf];
                    a = __builtin_amdgcn_mfma_f32_16x16x32_bf16(ahi[wr], bhi, a, 0, 0, 0);
                    a = __builtin_amdgcn_mfma_f32_16x16x32_bf16(ahi[wr], blo, a, 0, 0, 0);
                    a = __builtin_amdgcn_mfma_f32_16x16x32_bf16(alo[wr], bhi, a, 0, 0, 0);
                    acc[cs][wr][cf] = a;
                }
            }
        }
    }

    #pragma unroll
    for (int cs = 0; cs < NCS; ++cs)
        #pragma unroll
        for (int cf = 0; cf < 2; ++cf) {
            int c = cs * 32 + cf * 16 + rlo;
            #pragma unroll
            for (int wr = 0; wr < 2; ++wr)
                #pragma unroll
                for (int r = 0; r < 4; ++r) {
                    int row = row0 + wr * 16 + rhi * 4 + r;
                    if (row < M) {
                        float val = acc[cs][wr][cf][r];
                        if (c < SPLITC)
                            Cl[(size_t)row * SPLITC + c] = (__bf16)val;
                        else
                            Cr[(size_t)row * (NCS * 32 - SPLITC) + (c - SPLITC)] = val;
                    }
                }
        }
}

// ---------------- CSR build ----------------
__global__ void k_deg(const int* __restrict__ dst, int* __restrict__ deg, int E) {
    int e = blockIdx.x * blockDim.x + threadIdx.x;
    if (e < E) atomicAdd(&deg[dst[e]], 1);
}

__global__ __launch_bounds__(256) void k_scan1(const int* __restrict__ deg,
                                               int* __restrict__ offs,
                                               int* __restrict__ bsum, int n) {
    __shared__ int s[256];
    int t = threadIdx.x;
    int i = blockIdx.x * 256 + t;
    int v = (i < n) ? deg[i] : 0;
    s[t] = v;
    __syncthreads();
    for (int off = 1; off < 256; off <<= 1) {
        int add = (t >= off) ? s[t - off] : 0;
        __syncthreads();
        s[t] += add;
        __syncthreads();
    }
    if (i < n) offs[i] = s[t] - v;
    if (t == 255) bsum[blockIdx.x] = s[255];
}

__global__ __launch_bounds__(256) void k_scan2(int* __restrict__ bsum, int nb) {
    __shared__ int s[256];
    __shared__ int carry;
    int t = threadIdx.x;
    if (t == 0) carry = 0;
    __syncthreads();
    for (int base = 0; base < nb; base += 256) {
        int i = base + t;
        int v = (i < nb) ? bsum[i] : 0;
        s[t] = v;
        __syncthreads();
        for (int off = 1; off < 256; off <<= 1) {
            int add = (t >= off) ? s[t - off] : 0;
            __syncthreads();
            s[t] += add;
            __syncthreads();
        }
        if (i < nb) bsum[i] = s[t] - v + carry;
        __syncthreads();
        if (t == 0) carry += s[255];
        __syncthreads();
    }
}

__global__ void k_scan3(int* __restrict__ offs, const int* __restrict__ bsum,
                        int n, int E) {
    int i = blockIdx.x * blockDim.x + threadIdx.x;
    if (i < n) offs[i] += bsum[i >> 8];
    if (i == 0) offs[n] = E;
}

__global__ void k_bin(const int* __restrict__ src, const int* __restrict__ dst,
                      const int* __restrict__ offs, int* __restrict__ fill,
                      int* __restrict__ csr, int E) {
    int e = blockIdx.x * blockDim.x + threadIdx.x;
    if (e >= E) return;
    int d = dst[e];
    int pos = offs[d] + atomicAdd(&fill[d], 1);
    csr[pos] = src[e];
}

// ---------------- fused gather(bf16) + mean + lin_r + BN + ReLU ------------
// one wave per node; F=128: uint(2xbf16)/lane, F=64: ushort/lane
template <int LOGF>
__global__ __launch_bounds__(256) void k_agg(const __bf16* __restrict__ xl,
                                             const float* __restrict__ lin,
                                             const int* __restrict__ csr,
                                             const int* __restrict__ offs,
                                             const float* __restrict__ b,
                                             const float* __restrict__ g,
                                             const float* __restrict__ be,
                                             const float* __restrict__ m,
                                             const float* __restrict__ v,
                                             float* __restrict__ out, int N) {
    constexpr int F = 1 << LOGF;
    int node = blockIdx.x * 4 + (threadIdx.x >> 6);
    if (node >= N) return;
    int lane = threadIdx.x & 63;
    int beg = offs[node], end = offs[node + 1];
    float c = fmaxf((float)(end - beg), 1.0f);
    float inv = 1.0f / c;

    if constexpr (F == 128) {
        float sx = 0.f, sy = 0.f;
        const unsigned int* base = (const unsigned int*)xl;
        int e = beg;
        for (; e + 4 <= end; e += 4) {
            int s0 = csr[e], s1 = csr[e + 1], s2 = csr[e + 2], s3 = csr[e + 3];
            unsigned int t0 = base[(size_t)s0 * 64 + lane];
            unsigned int t1 = base[(size_t)s1 * 64 + lane];
            unsigned int t2 = base[(size_t)s2 * 64 + lane];
            unsigned int t3 = base[(size_t)s3 * 64 + lane];
            sx += __uint_as_float(t0 << 16) + __uint_as_float(t1 << 16) +
                  __uint_as_float(t2 << 16) + __uint_as_float(t3 << 16);
            sy += __uint_as_float(t0 & 0xffff0000u) + __uint_as_float(t1 & 0xffff0000u) +
                  __uint_as_float(t2 & 0xffff0000u) + __uint_as_float(t3 & 0xffff0000u);
        }
        for (; e < end; ++e) {
            unsigned int t0 = base[(size_t)csr[e] * 64 + lane];
            sx += __uint_as_float(t0 << 16);
            sy += __uint_as_float(t0 & 0xffff0000u);
        }
        int f0 = lane * 2;
        size_t o = (size_t)node * 128 + f0;
        float2 l2 = *(const float2*)(lin + o);
        float y0 = ((sx * inv + b[f0]     + l2.x) - m[f0])     * (g[f0]     * rsqrtf(v[f0]     + BN_EPS)) + be[f0];
        float y1 = ((sy * inv + b[f0 + 1] + l2.y) - m[f0 + 1]) * (g[f0 + 1] * rsqrtf(v[f0 + 1] + BN_EPS)) + be[f0 + 1];
        *(float2*)(out + o) = make_float2(fmaxf(y0, 0.f), fmaxf(y1, 0.f));
    } else {
        float s = 0.f;
        const unsigned short* base = (const unsigned short*)xl;
        int e = beg;
        for (; e + 4 <= end; e += 4) {
            int s0 = csr[e], s1 = csr[e + 1], s2 = csr[e + 2], s3 = csr[e + 3];
            unsigned int t0 = base[(size_t)s0 * 64 + lane];
            unsigned int t1 = base[(size_t)s1 * 64 + lane];
            unsigned int t2 = base[(size_t)s2 * 64 + lane];
            unsigned int t3 = base[(size_t)s3 * 64 + lane];
            s += __uint_as_float(t0 << 16) + __uint_as_float(t1 << 16) +
                 __uint_as_float(t2 << 16) + __uint_as_float(t3 << 16);
        }
        for (; e < end; ++e)
            s += __uint_as_float((unsigned int)base[(size_t)csr[e] * 64 + lane] << 16);
        size_t o = (size_t)node * 64 + lane;
        float y = ((s * inv + b[lane] + lin[o]) - m[lane]) * (g[lane] * rsqrtf(v[lane] + BN_EPS)) + be[lane];
        out[o] = fmaxf(y, 0.f);
    }
}

// ---------------- head: out[M,10] = h2[M,64] @ Wh[64,10] + bh --------------
__global__ __launch_bounds__(256) void k_head(const float* __restrict__ h2,
                                              const float* __restrict__ Wh,
                                              const float* __restrict__ bh,
                                              float* __restrict__ out, int M) {
    __shared__ float sW[64 * 10];
    __shared__ float sb[10];
    for (int i = threadIdx.x; i < 640; i += 256) sW[i] = Wh[i];
    if (threadIdx.x < 10) sb[threadIdx.x] = bh[threadIdx.x];
    __syncthreads();
    int n = blockIdx.x * blockDim.x + threadIdx.x;
    if (n >= M) return;
    float acc[10];
    #pragma unroll
    for (int c = 0; c < 10; ++c) acc[c] = sb[c];
    const float* hr = h2 + (size_t)n * 64;
    #pragma unroll
    for (int k = 0; k < 64; ++k) {
        float hv = hr[k];
        #pragma unroll
        for (int c = 0; c < 10; ++c) acc[c] = fmaf(hv, sW[k * 10 + c], acc[c]);
    }
    #pragma unroll
    for (int c = 0; c < 10; ++c) out[(size_t)n * 10 + c] = acc[c];
}

// ---------------------------------------------------------------------------
static inline size_t align256(size_t x) { return (x + 255) & ~(size_t)255; }

extern "C" void kernel_launch(void* const* d_in, const int* in_sizes, int n_in,
                              void* d_out, int out_size, void* d_ws, size_t ws_size,
                              hipStream_t stream) {
    const float* x   = (const float*)d_in[0];
    const void*  ei  = d_in[1];
    const float* W1l = (const float*)d_in[2];
    const float* b1l = (const float*)d_in[3];
    const float* W1r = (const float*)d_in[4];
    const float* g1  = (const float*)d_in[5];
    const float* be1 = (const float*)d_in[6];
    const float* m1  = (const float*)d_in[7];
    const float* v1  = (const float*)d_in[8];
    const float* W2l = (const float*)d_in[9];
    const float* b2l = (const float*)d_in[10];
    const float* W2r = (const float*)d_in[11];
    const float* g2  = (const float*)d_in[12];
    const float* be2 = (const float*)d_in[13];
    const float* m2  = (const float*)d_in[14];
    const float* v2  = (const float*)d_in[15];
    const float* Wh  = (const float*)d_in[16];
    const float* bh  = (const float*)d_in[17];
    float* out = (float*)d_out;

    const int N = N_NODES;
    const int E = in_sizes[1] / 2;
    const int NB = (N + 255) / 256;

    // -------- workspace layout --------
    char* p = (char*)d_ws;
    int* flag  = (int*)p;  p += 256;
    int* idx32 = (int*)p;  p += align256((size_t)2 * E * 4);
    int* csr   = (int*)p;  p += align256((size_t)E * 4);
    int* offs  = (int*)p;  p += align256((size_t)(N + 1) * 4);
    int* deg   = (int*)p;  p += align256((size_t)N * 4);
    int* fill  = (int*)p;  p += align256((size_t)N * 4);
    int* bsum  = (int*)p;  p += 4096;
    __bf16* Wt1hi = (__bf16*)p; p += align256((size_t)256 * 128 * 2);
    __bf16* Wt1lo = (__bf16*)p; p += align256((size_t)256 * 128 * 2);
    __bf16* Wt2hi = (__bf16*)p; p += align256((size_t)128 * 128 * 2);
    __bf16* Wt2lo = (__bf16*)p; p += align256((size_t)128 * 128 * 2);
    __bf16* xl = (__bf16*)p; p += align256((size_t)N * 128 * 2);  // bf16 gather src
    float* xr  = (float*)p;  p += (size_t)N * 128 * 4;
    float* h   = (float*)p;  p += (size_t)N * 128 * 4;
    int* src32 = idx32;
    int* dst32 = idx32 + E;
    // layer-2 reuse
    __bf16* t2l = xl;                    // [N,64] bf16
    float* t2r  = xr;                    // [N,64] f32
    float* h2   = h;                     // [N,64] f32

    dim3 blk(256);

    // -------- normalize edge indices to int32 --------
    int nwords = 4 * E < 8192 ? 4 * E : 8192;
    k_detect_idx<<<dim3(1), blk, 0, stream>>>((const unsigned int*)ei, nwords, flag);
    {
        int n2 = 2 * E;
        k_convert_idx<<<dim3((n2 + 255) / 256), blk, 0, stream>>>(
            (const unsigned int*)ei, n2, flag, idx32);
    }

    // -------- CSR build --------
    hipMemsetAsync(deg, 0, (size_t)N * 4, stream);
    hipMemsetAsync(fill, 0, (size_t)N * 4, stream);
    k_deg<<<dim3((E + 255) / 256), blk, 0, stream>>>(dst32, deg, E);
    k_scan1<<<dim3(NB), blk, 0, stream>>>(deg, offs, bsum, N);
    k_scan2<<<dim3(1), blk, 0, stream>>>(bsum, NB);
    k_scan3<<<dim3(NB), blk, 0, stream>>>(offs, bsum, N, E);
    k_bin<<<dim3((E + 255) / 256), blk, 0, stream>>>(src32, dst32, offs, fill, csr, E);

    // -------- weight prep --------
    k_wprep<<<dim3((2 * 128 * 128 + 255) / 256), blk, 0, stream>>>(W1l, W1r, 128, 128, Wt1hi, Wt1lo);
    k_wprep<<<dim3((2 * 64 * 128 + 255) / 256), blk, 0, stream>>>(W2l, W2r, 128, 64, Wt2hi, Wt2lo);

    // -------- layer 1: bf16x3 MFMA GEMMs --------
    dim3 ggrid((N + 127) / 128);
    k_mfma<128, 4, 128><<<ggrid, blk, 0, stream>>>(x, Wt1hi, Wt1lo, xl, (float*)nullptr, N);
    k_mfma<128, 4, 0><<<ggrid, blk, 0, stream>>>(x, Wt1hi + 128 * 128, Wt1lo + 128 * 128,
                                                 (__bf16*)nullptr, xr, N);
    k_agg<7><<<dim3((N + 3) / 4), blk, 0, stream>>>(
        xl, xr, csr, offs, b1l, g1, be1, m1, v1, h, N);

    // -------- layer 2 --------
    k_mfma<128, 4, 64><<<ggrid, blk, 0, stream>>>(h, Wt2hi, Wt2lo, t2l, t2r, N);
    k_agg<6><<<dim3((N + 3) / 4), blk, 0, stream>>>(
        t2l, t2r, csr, offs, b2l, g2, be2, m2, v2, h2, N);

    // -------- head --------
    k_head<<<dim3((N + 255) / 256), blk, 0, stream>>>(h2, Wh, bh, out, N);
}

// Round 4
// 449.780 us; speedup vs baseline: 3.3272x; 1.0803x over previous
//
#include <hip/hip_runtime.h>
#include <hip/hip_bf16.h>
#include <stdint.h>

#define N_NODES 100000
constexpr float BN_EPS = 1e-5f;

typedef __bf16 bf16x8 __attribute__((ext_vector_type(8)));
typedef float f32x4 __attribute__((ext_vector_type(4)));

// ---------------- edge-index dtype detection ----------------
__global__ void k_detect_idx(const unsigned int* __restrict__ w, int nwords,
                             int* __restrict__ flag) {
    __shared__ int s;
    if (threadIdx.x == 0) s = 0;
    __syncthreads();
    for (int i = 1 + 2 * (int)threadIdx.x; i < nwords; i += 2 * (int)blockDim.x)
        if (w[i] != 0u) s = 1;
    __syncthreads();
    if (threadIdx.x == 0) *flag = s;   // 1 => int32, 0 => int64
}

// ---------------- fused convert + rank + degree ----------------
__global__ void k_prep(const unsigned int* __restrict__ w, int E,
                       const int* __restrict__ flag,
                       int* __restrict__ idx32, int* __restrict__ rank,
                       int* __restrict__ deg) {
    int e = blockIdx.x * blockDim.x + threadIdx.x;
    if (e >= E) return;
    int f = *flag;
    int s = (int)(f ? w[e] : w[2 * (size_t)e]);
    int d = (int)(f ? w[E + e] : w[2 * ((size_t)E + e)]);
    idx32[e] = s;
    idx32[E + e] = d;
    rank[e] = atomicAdd(&deg[d], 1);
}

// ---------------- scans ----------------
__global__ __launch_bounds__(256) void k_scan1(const int* __restrict__ deg,
                                               int* __restrict__ offs,
                                               int* __restrict__ bsum, int n) {
    __shared__ int s[256];
    int t = threadIdx.x;
    int i = blockIdx.x * 256 + t;
    int v = (i < n) ? deg[i] : 0;
    s[t] = v;
    __syncthreads();
    for (int off = 1; off < 256; off <<= 1) {
        int add = (t >= off) ? s[t - off] : 0;
        __syncthreads();
        s[t] += add;
        __syncthreads();
    }
    if (i < n) offs[i] = s[t] - v;
    if (t == 255) bsum[blockIdx.x] = s[255];
}

__global__ __launch_bounds__(256) void k_scan2(int* __restrict__ bsum, int nb) {
    __shared__ int s[256];
    __shared__ int carry;
    int t = threadIdx.x;
    if (t == 0) carry = 0;
    __syncthreads();
    for (int base = 0; base < nb; base += 256) {
        int i = base + t;
        int v = (i < nb) ? bsum[i] : 0;
        s[t] = v;
        __syncthreads();
        for (int off = 1; off < 256; off <<= 1) {
            int add = (t >= off) ? s[t - off] : 0;
            __syncthreads();
            s[t] += add;
            __syncthreads();
        }
        if (i < nb) bsum[i] = s[t] - v + carry;
        __syncthreads();
        if (t == 0) carry += s[255];
        __syncthreads();
    }
}

__global__ void k_scan3(int* __restrict__ offs, const int* __restrict__ bsum,
                        int n, int E) {
    int i = blockIdx.x * blockDim.x + threadIdx.x;
    if (i < n) offs[i] += bsum[i >> 8];
    if (i == 0) offs[n] = E;
}

// ---------------- CSR scatter (no atomic) ----------------
__global__ void k_bin2(const int* __restrict__ idx32, const int* __restrict__ rank,
                       const int* __restrict__ offs, int* __restrict__ csr, int E) {
    int e = blockIdx.x * blockDim.x + threadIdx.x;
    if (e >= E) return;
    int d = idx32[E + e];
    csr[offs[d] + rank[e]] = idx32[e];
}

// ---------------- W prep: split fp32 W into bf16 hi/lo, transposed ----------
__global__ void k_wprep(const float* __restrict__ Wl, const float* __restrict__ Wr,
                        int K, int halfN, __bf16* __restrict__ Wthi,
                        __bf16* __restrict__ Wtlo) {
    int idx = blockIdx.x * 256 + threadIdx.x;
    int total = 2 * halfN * K;
    if (idx >= total) return;
    int c = idx / K, k = idx - c * K;
    const float* W = (c < halfN) ? Wl : Wr;
    int cc = (c < halfN) ? c : c - halfN;
    float v = W[(size_t)k * halfN + cc];
    __bf16 h = (__bf16)v;
    Wthi[idx] = h;
    Wtlo[idx] = (__bf16)(v - (float)h);
}

// ---------------- bf16x3 MFMA GEMM: C = A[f32] @ W ------------
// Block = 4 waves, wave owns 32 rows x NCS*32 cols.
// cols [0,SPLITC) -> Cl (bf16, stride SPLITC); rest -> Cr (f32).
template <int K, int NCS, int SPLITC>
__global__ __launch_bounds__(256) void k_mfma(const float* __restrict__ A,
                                              const __bf16* __restrict__ Wthi,
                                              const __bf16* __restrict__ Wtlo,
                                              __bf16* __restrict__ Cl,
                                              float* __restrict__ Cr,
                                              int M) {
    const int lane = threadIdx.x & 63;
    const int wave = threadIdx.x >> 6;
    const int row0 = blockIdx.x * 128 + wave * 32;
    const int rlo = lane & 15;
    const int rhi = lane >> 4;            // 0..3

    f32x4 acc[NCS][2][2] = {};

    for (int k0 = 0; k0 < K; k0 += 32) {
        bf16x8 ahi[2], alo[2];
        #pragma unroll
        for (int wr = 0; wr < 2; ++wr) {
            int row = row0 + wr * 16 + rlo;
            row = row < M ? row : M - 1;
            const float* ap = A + (size_t)row * K + k0 + rhi * 8;
            float4 v0 = *(const float4*)ap;
            float4 v1 = *(const float4*)(ap + 4);
            float vv[8] = {v0.x, v0.y, v0.z, v0.w, v1.x, v1.y, v1.z, v1.w};
            #pragma unroll
            for (int i = 0; i < 8; ++i) {
                __bf16 h = (__bf16)vv[i];
                ahi[wr][i] = h;
                alo[wr][i] = (__bf16)(vv[i] - (float)h);
            }
        }
        #pragma unroll
        for (int cs = 0; cs < NCS; ++cs) {
            #pragma unroll
            for (int cf = 0; cf < 2; ++cf) {
                int c = cs * 32 + cf * 16 + rlo;
                size_t boff = (size_t)c * K + k0 + rhi * 8;
                bf16x8 bhi = *(const bf16x8*)(Wthi + boff);
                bf16x8 blo = *(const bf16x8*)(Wtlo + boff);
                #pragma unroll
                for (int wr = 0; wr < 2; ++wr) {
                    f32x4 a = acc[cs][wr][cf];
                    a = __builtin_amdgcn_mfma_f32_16x16x32_bf16(ahi[wr], bhi, a, 0, 0, 0);
                    a = __builtin_amdgcn_mfma_f32_16x16x32_bf16(ahi[wr], blo, a, 0, 0, 0);
                    a = __builtin_amdgcn_mfma_f32_16x16x32_bf16(alo[wr], bhi, a, 0, 0, 0);
                    acc[cs][wr][cf] = a;
                }
            }
        }
    }

    #pragma unroll
    for (int cs = 0; cs < NCS; ++cs)
        #pragma unroll
        for (int cf = 0; cf < 2; ++cf) {
            int c = cs * 32 + cf * 16 + rlo;
            #pragma unroll
            for (int wr = 0; wr < 2; ++wr)
                #pragma unroll
                for (int r = 0; r < 4; ++r) {
                    int row = row0 + wr * 16 + rhi * 4 + r;
                    if (row < M) {
                        float val = acc[cs][wr][cf][r];
                        if (c < SPLITC)
                            Cl[(size_t)row * SPLITC + c] = (__bf16)val;
                        else
                            Cr[(size_t)row * (NCS * 32 - SPLITC) + (c - SPLITC)] = val;
                    }
                }
        }
}

// ---------------- wave reduction ----------------
__device__ inline float wave_red_sum(float v) {
    #pragma unroll
    for (int off = 32; off; off >>= 1) v += __shfl_xor(v, off, 64);
    return v;
}

// ---------------- fused gather(bf16) + mean + lin_r + BN + ReLU [+ head] ---
template <int LOGF, bool HEAD>
__global__ __launch_bounds__(256) void k_agg(const __bf16* __restrict__ xl,
                                             const float* __restrict__ lin,
                                             const int* __restrict__ csr,
                                             const int* __restrict__ offs,
                                             const float* __restrict__ b,
                                             const float* __restrict__ g,
                                             const float* __restrict__ be,
                                             const float* __restrict__ m,
                                             const float* __restrict__ v,
                                             float* __restrict__ out,
                                             const float* __restrict__ Wh,
                                             const float* __restrict__ bh,
                                             int N) {
    constexpr int F = 1 << LOGF;
    int node = blockIdx.x * 4 + (threadIdx.x >> 6);
    if (node >= N) return;
    int lane = threadIdx.x & 63;
    int beg = offs[node], end = offs[node + 1];
    float c = fmaxf((float)(end - beg), 1.0f);
    float inv = 1.0f / c;

    if constexpr (F == 128) {
        float sx = 0.f, sy = 0.f;
        const unsigned int* base = (const unsigned int*)xl;
        int e = beg;
        for (; e + 8 <= end; e += 8) {
            unsigned int t[8];
            #pragma unroll
            for (int u = 0; u < 8; ++u)
                t[u] = base[(size_t)csr[e + u] * 64 + lane];
            #pragma unroll
            for (int u = 0; u < 8; ++u) {
                sx += __uint_as_float(t[u] << 16);
                sy += __uint_as_float(t[u] & 0xffff0000u);
            }
        }
        for (; e < end; ++e) {
            unsigned int t0 = base[(size_t)csr[e] * 64 + lane];
            sx += __uint_as_float(t0 << 16);
            sy += __uint_as_float(t0 & 0xffff0000u);
        }
        int f0 = lane * 2;
        size_t o = (size_t)node * 128 + f0;
        float2 l2 = *(const float2*)(lin + o);
        float y0 = ((sx * inv + b[f0]     + l2.x) - m[f0])     * (g[f0]     * rsqrtf(v[f0]     + BN_EPS)) + be[f0];
        float y1 = ((sy * inv + b[f0 + 1] + l2.y) - m[f0 + 1]) * (g[f0 + 1] * rsqrtf(v[f0 + 1] + BN_EPS)) + be[f0 + 1];
        *(float2*)(out + o) = make_float2(fmaxf(y0, 0.f), fmaxf(y1, 0.f));
    } else {
        float s = 0.f;
        const unsigned short* base = (const unsigned short*)xl;
        int e = beg;
        for (; e + 8 <= end; e += 8) {
            unsigned int t[8];
            #pragma unroll
            for (int u = 0; u < 8; ++u)
                t[u] = base[(size_t)csr[e + u] * 64 + lane];
            #pragma unroll
            for (int u = 0; u < 8; ++u)
                s += __uint_as_float(t[u] << 16);
        }
        for (; e < end; ++e)
            s += __uint_as_float((unsigned int)base[(size_t)csr[e] * 64 + lane] << 16);
        size_t o = (size_t)node * 64 + lane;
        float y = ((s * inv + b[lane] + lin[o]) - m[lane]) * (g[lane] * rsqrtf(v[lane] + BN_EPS)) + be[lane];
        y = fmaxf(y, 0.f);
        if constexpr (HEAD) {
            // out[node, c] = sum_l y_l * Wh[l, c] + bh[c]
            #pragma unroll
            for (int cc = 0; cc < 10; ++cc) {
                float p = wave_red_sum(y * Wh[lane * 10 + cc]);
                if (lane == 0) out[(size_t)node * 10 + cc] = p + bh[cc];
            }
        } else {
            out[o] = y;
        }
    }
}

// ---------------------------------------------------------------------------
static inline size_t align256(size_t x) { return (x + 255) & ~(size_t)255; }

extern "C" void kernel_launch(void* const* d_in, const int* in_sizes, int n_in,
                              void* d_out, int out_size, void* d_ws, size_t ws_size,
                              hipStream_t stream) {
    const float* x   = (const float*)d_in[0];
    const void*  ei  = d_in[1];
    const float* W1l = (const float*)d_in[2];
    const float* b1l = (const float*)d_in[3];
    const float* W1r = (const float*)d_in[4];
    const float* g1  = (const float*)d_in[5];
    const float* be1 = (const float*)d_in[6];
    const float* m1  = (const float*)d_in[7];
    const float* v1  = (const float*)d_in[8];
    const float* W2l = (const float*)d_in[9];
    const float* b2l = (const float*)d_in[10];
    const float* W2r = (const float*)d_in[11];
    const float* g2  = (const float*)d_in[12];
    const float* be2 = (const float*)d_in[13];
    const float* m2  = (const float*)d_in[14];
    const float* v2  = (const float*)d_in[15];
    const float* Wh  = (const float*)d_in[16];
    const float* bh  = (const float*)d_in[17];
    float* out = (float*)d_out;

    const int N = N_NODES;
    const int E = in_sizes[1] / 2;
    const int NB = (N + 255) / 256;

    // -------- workspace layout --------
    char* p = (char*)d_ws;
    int* flag  = (int*)p;  p += 256;
    int* idx32 = (int*)p;  p += align256((size_t)2 * E * 4);
    int* rank  = (int*)p;  p += align256((size_t)E * 4);
    int* csr   = (int*)p;  p += align256((size_t)E * 4);
    int* offs  = (int*)p;  p += align256((size_t)(N + 1) * 4);
    int* deg   = (int*)p;  p += align256((size_t)N * 4);
    int* bsum  = (int*)p;  p += 4096;
    __bf16* Wt1hi = (__bf16*)p; p += align256((size_t)256 * 128 * 2);
    __bf16* Wt1lo = (__bf16*)p; p += align256((size_t)256 * 128 * 2);
    __bf16* Wt2hi = (__bf16*)p; p += align256((size_t)128 * 128 * 2);
    __bf16* Wt2lo = (__bf16*)p; p += align256((size_t)128 * 128 * 2);
    __bf16* xl = (__bf16*)p; p += align256((size_t)N * 128 * 2);
    float* xr  = (float*)p;  p += (size_t)N * 128 * 4;
    float* h   = (float*)p;  p += (size_t)N * 128 * 4;
    // layer-2 reuse
    __bf16* t2l = xl;                    // [N,64] bf16
    float* t2r  = xr;                    // [N,64] f32

    dim3 blk(256);

    // -------- edge prep: detect dtype, convert + rank + degree --------
    int nwords = 4 * E < 8192 ? 4 * E : 8192;
    k_detect_idx<<<dim3(1), blk, 0, stream>>>((const unsigned int*)ei, nwords, flag);
    hipMemsetAsync(deg, 0, (size_t)N * 4, stream);
    k_prep<<<dim3((E + 255) / 256), blk, 0, stream>>>(
        (const unsigned int*)ei, E, flag, idx32, rank, deg);

    // -------- scan + CSR scatter --------
    k_scan1<<<dim3(NB), blk, 0, stream>>>(deg, offs, bsum, N);
    k_scan2<<<dim3(1), blk, 0, stream>>>(bsum, NB);
    k_scan3<<<dim3(NB), blk, 0, stream>>>(offs, bsum, N, E);
    k_bin2<<<dim3((E + 255) / 256), blk, 0, stream>>>(idx32, rank, offs, csr, E);

    // -------- weight prep --------
    k_wprep<<<dim3((2 * 128 * 128 + 255) / 256), blk, 0, stream>>>(W1l, W1r, 128, 128, Wt1hi, Wt1lo);
    k_wprep<<<dim3((2 * 64 * 128 + 255) / 256), blk, 0, stream>>>(W2l, W2r, 128, 64, Wt2hi, Wt2lo);

    // -------- layer 1: fused dual GEMM (reads x once) --------
    dim3 ggrid((N + 127) / 128);
    k_mfma<128, 8, 128><<<ggrid, blk, 0, stream>>>(x, Wt1hi, Wt1lo, xl, xr, N);
    k_agg<7, false><<<dim3((N + 3) / 4), blk, 0, stream>>>(
        xl, xr, csr, offs, b1l, g1, be1, m1, v1, h, nullptr, nullptr, N);

    // -------- layer 2 + fused head --------
    k_mfma<128, 4, 64><<<ggrid, blk, 0, stream>>>(h, Wt2hi, Wt2lo, t2l, t2r, N);
    k_agg<6, true><<<dim3((N + 3) / 4), blk, 0, stream>>>(
        t2l, t2r, csr, offs, b2l, g2, be2, m2, v2, out, Wh, bh, N);
}

// Round 5
// 372.919 us; speedup vs baseline: 4.0130x; 1.2061x over previous
//
#include <hip/hip_runtime.h>
#include <hip/hip_bf16.h>
#include <stdint.h>

#define N_NODES 100000
constexpr float BN_EPS = 1e-5f;

typedef __bf16 bf16x8 __attribute__((ext_vector_type(8)));
typedef float f32x4 __attribute__((ext_vector_type(4)));

// ---------------- edge-index dtype detection ----------------
__global__ void k_detect_idx(const unsigned int* __restrict__ w, int nwords,
                             int* __restrict__ flag) {
    __shared__ int s;
    if (threadIdx.x == 0) s = 0;
    __syncthreads();
    for (int i = 1 + 2 * (int)threadIdx.x; i < nwords; i += 2 * (int)blockDim.x)
        if (w[i] != 0u) s = 1;
    __syncthreads();
    if (threadIdx.x == 0) *flag = s;   // 1 => int32, 0 => int64
}

// ---------------- fused convert + rank + degree ----------------
__global__ void k_prep(const unsigned int* __restrict__ w, int E,
                       const int* __restrict__ flag,
                       int* __restrict__ idx32, int* __restrict__ rank,
                       int* __restrict__ deg) {
    int e = blockIdx.x * blockDim.x + threadIdx.x;
    if (e >= E) return;
    int f = *flag;
    int s = (int)(f ? w[e] : w[2 * (size_t)e]);
    int d = (int)(f ? w[E + e] : w[2 * ((size_t)E + e)]);
    idx32[e] = s;
    idx32[E + e] = d;
    rank[e] = atomicAdd(&deg[d], 1);
}

// ---------------- scans ----------------
__global__ __launch_bounds__(256) void k_scan1(const int* __restrict__ deg,
                                               int* __restrict__ offs,
                                               int* __restrict__ bsum, int n) {
    __shared__ int s[256];
    int t = threadIdx.x;
    int i = blockIdx.x * 256 + t;
    int v = (i < n) ? deg[i] : 0;
    s[t] = v;
    __syncthreads();
    for (int off = 1; off < 256; off <<= 1) {
        int add = (t >= off) ? s[t - off] : 0;
        __syncthreads();
        s[t] += add;
        __syncthreads();
    }
    if (i < n) offs[i] = s[t] - v;
    if (t == 255) bsum[blockIdx.x] = s[255];
}

__global__ __launch_bounds__(256) void k_scan2(int* __restrict__ bsum, int nb) {
    __shared__ int s[256];
    __shared__ int carry;
    int t = threadIdx.x;
    if (t == 0) carry = 0;
    __syncthreads();
    for (int base = 0; base < nb; base += 256) {
        int i = base + t;
        int v = (i < nb) ? bsum[i] : 0;
        s[t] = v;
        __syncthreads();
        for (int off = 1; off < 256; off <<= 1) {
            int add = (t >= off) ? s[t - off] : 0;
            __syncthreads();
            s[t] += add;
            __syncthreads();
        }
        if (i < nb) bsum[i] = s[t] - v + carry;
        __syncthreads();
        if (t == 0) carry += s[255];
        __syncthreads();
    }
}

__global__ void k_scan3(int* __restrict__ offs, const int* __restrict__ bsum,
                        int n, int E) {
    int i = blockIdx.x * blockDim.x + threadIdx.x;
    if (i < n) offs[i] += bsum[i >> 8];
    if (i == 0) offs[n] = E;
}

// ---------------- W prep: split fp32 W into bf16 hi/lo, transposed ----------
__global__ void k_wprep(const float* __restrict__ Wl, const float* __restrict__ Wr,
                        int K, int halfN, __bf16* __restrict__ Wthi,
                        __bf16* __restrict__ Wtlo) {
    int idx = blockIdx.x * 256 + threadIdx.x;
    int total = 2 * halfN * K;
    if (idx >= total) return;
    int c = idx / K, k = idx - c * K;
    const float* W = (c < halfN) ? Wl : Wr;
    int cc = (c < halfN) ? c : c - halfN;
    float v = W[(size_t)k * halfN + cc];
    __bf16 h = (__bf16)v;
    Wthi[idx] = h;
    Wtlo[idx] = (__bf16)(v - (float)h);
}

// ---------------- bf16x3 MFMA GEMM body (device) ------------
template <int K, int NCS, int SPLITC>
__device__ void mfma_body(const float* __restrict__ A,
                          const __bf16* __restrict__ Wthi,
                          const __bf16* __restrict__ Wtlo,
                          __bf16* __restrict__ Cl, float* __restrict__ Cr,
                          int M, int bid) {
    const int lane = threadIdx.x & 63;
    const int wave = threadIdx.x >> 6;
    const int row0 = bid * 128 + wave * 32;
    const int rlo = lane & 15;
    const int rhi = lane >> 4;            // 0..3

    f32x4 acc[NCS][2][2] = {};

    for (int k0 = 0; k0 < K; k0 += 32) {
        bf16x8 ahi[2], alo[2];
        #pragma unroll
        for (int wr = 0; wr < 2; ++wr) {
            int row = row0 + wr * 16 + rlo;
            row = row < M ? row : M - 1;
            const float* ap = A + (size_t)row * K + k0 + rhi * 8;
            float4 v0 = *(const float4*)ap;
            float4 v1 = *(const float4*)(ap + 4);
            float vv[8] = {v0.x, v0.y, v0.z, v0.w, v1.x, v1.y, v1.z, v1.w};
            #pragma unroll
            for (int i = 0; i < 8; ++i) {
                __bf16 h = (__bf16)vv[i];
                ahi[wr][i] = h;
                alo[wr][i] = (__bf16)(vv[i] - (float)h);
            }
        }
        #pragma unroll
        for (int cs = 0; cs < NCS; ++cs) {
            #pragma unroll
            for (int cf = 0; cf < 2; ++cf) {
                int c = cs * 32 + cf * 16 + rlo;
                size_t boff = (size_t)c * K + k0 + rhi * 8;
                bf16x8 bhi = *(const bf16x8*)(Wthi + boff);
                bf16x8 blo = *(const bf16x8*)(Wtlo + boff);
                #pragma unroll
                for (int wr = 0; wr < 2; ++wr) {
                    f32x4 a = acc[cs][wr][cf];
                    a = __builtin_amdgcn_mfma_f32_16x16x32_bf16(ahi[wr], bhi, a, 0, 0, 0);
                    a = __builtin_amdgcn_mfma_f32_16x16x32_bf16(ahi[wr], blo, a, 0, 0, 0);
                    a = __builtin_amdgcn_mfma_f32_16x16x32_bf16(alo[wr], bhi, a, 0, 0, 0);
                    acc[cs][wr][cf] = a;
                }
            }
        }
    }

    #pragma unroll
    for (int cs = 0; cs < NCS; ++cs)
        #pragma unroll
        for (int cf = 0; cf < 2; ++cf) {
            int c = cs * 32 + cf * 16 + rlo;
            #pragma unroll
            for (int wr = 0; wr < 2; ++wr)
                #pragma unroll
                for (int r = 0; r < 4; ++r) {
                    int row = row0 + wr * 16 + rhi * 4 + r;
                    if (row < M) {
                        float val = acc[cs][wr][cf][r];
                        if (c < SPLITC)
                            Cl[(size_t)row * SPLITC + c] = (__bf16)val;
                        else
                            Cr[(size_t)row * (NCS * 32 - SPLITC) + (c - SPLITC)] = val;
                    }
                }
        }
}

// plain GEMM kernel (layer 2)
template <int K, int NCS, int SPLITC>
__global__ __launch_bounds__(256) void k_mfma(const float* __restrict__ A,
                                              const __bf16* __restrict__ Wthi,
                                              const __bf16* __restrict__ Wtlo,
                                              __bf16* __restrict__ Cl,
                                              float* __restrict__ Cr, int M) {
    mfma_body<K, NCS, SPLITC>(A, Wthi, Wtlo, Cl, Cr, M, blockIdx.x);
}

// fused GEMM + CSR-scatter (independent work co-scheduled on the GPU)
template <int K, int NCS, int SPLITC>
__global__ __launch_bounds__(256) void k_mfma_bin(const float* __restrict__ A,
                                                  const __bf16* __restrict__ Wthi,
                                                  const __bf16* __restrict__ Wtlo,
                                                  __bf16* __restrict__ Cl,
                                                  float* __restrict__ Cr, int M,
                                                  int gemmBlocks,
                                                  const int* __restrict__ idx32,
                                                  const int* __restrict__ rank,
                                                  const int* __restrict__ offs,
                                                  int* __restrict__ csr, int E) {
    if ((int)blockIdx.x >= gemmBlocks) {
        int e = (blockIdx.x - gemmBlocks) * 256 + threadIdx.x;
        if (e < E) {
            int d = idx32[E + e];
            csr[offs[d] + rank[e]] = idx32[e];
        }
        return;
    }
    mfma_body<K, NCS, SPLITC>(A, Wthi, Wtlo, Cl, Cr, M, blockIdx.x);
}

// ---------------- fused gather(bf16) + mean + lin_r + BN + ReLU ------------
// one wave per node; cooperative coalesced csr loads + __shfl broadcast
template <int LOGF>
__global__ __launch_bounds__(256) void k_agg(const __bf16* __restrict__ xl,
                                             const float* __restrict__ lin,
                                             const int* __restrict__ csr,
                                             const int* __restrict__ offs,
                                             const float* __restrict__ b,
                                             const float* __restrict__ g,
                                             const float* __restrict__ be,
                                             const float* __restrict__ m,
                                             const float* __restrict__ v,
                                             float* __restrict__ out, int N) {
    constexpr int F = 1 << LOGF;
    int node = blockIdx.x * 4 + (threadIdx.x >> 6);
    if (node >= N) return;
    int lane = threadIdx.x & 63;
    int beg = offs[node], end = offs[node + 1];
    float inv = 1.0f / fmaxf((float)(end - beg), 1.0f);

    if constexpr (F == 128) {
        float sx = 0.f, sy = 0.f;
        const unsigned int* base = (const unsigned int*)xl;
        int e = beg;
        while (e < end) {
            int bl = min(64, end - e);
            int myidx = (lane < bl) ? csr[e + lane] : 0;
            int u = 0;
            for (; u + 8 <= bl; u += 8) {
                unsigned int t[8];
                #pragma unroll
                for (int i = 0; i < 8; ++i) {
                    int sidx = __shfl(myidx, u + i, 64);
                    t[i] = base[(size_t)sidx * 64 + lane];
                }
                #pragma unroll
                for (int i = 0; i < 8; ++i) {
                    sx += __uint_as_float(t[i] << 16);
                    sy += __uint_as_float(t[i] & 0xffff0000u);
                }
            }
            for (; u < bl; ++u) {
                int sidx = __shfl(myidx, u, 64);
                unsigned int t = base[(size_t)sidx * 64 + lane];
                sx += __uint_as_float(t << 16);
                sy += __uint_as_float(t & 0xffff0000u);
            }
            e += bl;
        }
        int f0 = lane * 2;
        size_t o = (size_t)node * 128 + f0;
        float2 l2 = *(const float2*)(lin + o);
        float y0 = ((sx * inv + b[f0]     + l2.x) - m[f0])     * (g[f0]     * rsqrtf(v[f0]     + BN_EPS)) + be[f0];
        float y1 = ((sy * inv + b[f0 + 1] + l2.y) - m[f0 + 1]) * (g[f0 + 1] * rsqrtf(v[f0 + 1] + BN_EPS)) + be[f0 + 1];
        *(float2*)(out + o) = make_float2(fmaxf(y0, 0.f), fmaxf(y1, 0.f));
    } else {
        float s = 0.f;
        const unsigned short* base = (const unsigned short*)xl;
        int e = beg;
        while (e < end) {
            int bl = min(64, end - e);
            int myidx = (lane < bl) ? csr[e + lane] : 0;
            int u = 0;
            for (; u + 8 <= bl; u += 8) {
                unsigned int t[8];
                #pragma unroll
                for (int i = 0; i < 8; ++i) {
                    int sidx = __shfl(myidx, u + i, 64);
                    t[i] = base[(size_t)sidx * 64 + lane];
                }
                #pragma unroll
                for (int i = 0; i < 8; ++i)
                    s += __uint_as_float(t[i] << 16);
            }
            for (; u < bl; ++u) {
                int sidx = __shfl(myidx, u, 64);
                s += __uint_as_float((unsigned int)base[(size_t)sidx * 64 + lane] << 16);
            }
            e += bl;
        }
        size_t o = (size_t)node * 64 + lane;
        float y = ((s * inv + b[lane] + lin[o]) - m[lane]) * (g[lane] * rsqrtf(v[lane] + BN_EPS)) + be[lane];
        out[o] = fmaxf(y, 0.f);
    }
}

// ---------------- head: out[M,10] = h2[M,64] @ Wh[64,10] + bh --------------
__global__ __launch_bounds__(256) void k_head(const float* __restrict__ h2,
                                              const float* __restrict__ Wh,
                                              const float* __restrict__ bh,
                                              float* __restrict__ out, int M) {
    __shared__ float sW[64 * 10];
    __shared__ float sb[10];
    for (int i = threadIdx.x; i < 640; i += 256) sW[i] = Wh[i];
    if (threadIdx.x < 10) sb[threadIdx.x] = bh[threadIdx.x];
    __syncthreads();
    int n = blockIdx.x * blockDim.x + threadIdx.x;
    if (n >= M) return;
    float acc[10];
    #pragma unroll
    for (int c = 0; c < 10; ++c) acc[c] = sb[c];
    const float* hr = h2 + (size_t)n * 64;
    #pragma unroll
    for (int k = 0; k < 64; ++k) {
        float hv = hr[k];
        #pragma unroll
        for (int c = 0; c < 10; ++c) acc[c] = fmaf(hv, sW[k * 10 + c], acc[c]);
    }
    #pragma unroll
    for (int c = 0; c < 10; ++c) out[(size_t)n * 10 + c] = acc[c];
}

// ---------------------------------------------------------------------------
static inline size_t align256(size_t x) { return (x + 255) & ~(size_t)255; }

extern "C" void kernel_launch(void* const* d_in, const int* in_sizes, int n_in,
                              void* d_out, int out_size, void* d_ws, size_t ws_size,
                              hipStream_t stream) {
    const float* x   = (const float*)d_in[0];
    const void*  ei  = d_in[1];
    const float* W1l = (const float*)d_in[2];
    const float* b1l = (const float*)d_in[3];
    const float* W1r = (const float*)d_in[4];
    const float* g1  = (const float*)d_in[5];
    const float* be1 = (const float*)d_in[6];
    const float* m1  = (const float*)d_in[7];
    const float* v1  = (const float*)d_in[8];
    const float* W2l = (const float*)d_in[9];
    const float* b2l = (const float*)d_in[10];
    const float* W2r = (const float*)d_in[11];
    const float* g2  = (const float*)d_in[12];
    const float* be2 = (const float*)d_in[13];
    const float* m2  = (const float*)d_in[14];
    const float* v2  = (const float*)d_in[15];
    const float* Wh  = (const float*)d_in[16];
    const float* bh  = (const float*)d_in[17];
    float* out = (float*)d_out;

    const int N = N_NODES;
    const int E = in_sizes[1] / 2;
    const int NB = (N + 255) / 256;

    // -------- workspace layout --------
    char* p = (char*)d_ws;
    int* flag  = (int*)p;  p += 256;
    int* idx32 = (int*)p;  p += align256((size_t)2 * E * 4);
    int* rank  = (int*)p;  p += align256((size_t)E * 4);
    int* csr   = (int*)p;  p += align256((size_t)E * 4);
    int* offs  = (int*)p;  p += align256((size_t)(N + 1) * 4);
    int* deg   = (int*)p;  p += align256((size_t)N * 4);
    int* bsum  = (int*)p;  p += 4096;
    __bf16* Wt1hi = (__bf16*)p; p += align256((size_t)256 * 128 * 2);
    __bf16* Wt1lo = (__bf16*)p; p += align256((size_t)256 * 128 * 2);
    __bf16* Wt2hi = (__bf16*)p; p += align256((size_t)128 * 128 * 2);
    __bf16* Wt2lo = (__bf16*)p; p += align256((size_t)128 * 128 * 2);
    __bf16* xl = (__bf16*)p; p += align256((size_t)N * 128 * 2);
    float* xr  = (float*)p;  p += (size_t)N * 128 * 4;
    float* h   = (float*)p;  p += (size_t)N * 128 * 4;
    // layer-2 reuse
    __bf16* t2l = xl;                    // [N,64] bf16
    float* t2r  = xr;                    // [N,64] f32
    float* h2   = h;                     // [N,64] f32 (h dead after mfma2)

    dim3 blk(256);

    // -------- edge prep: detect dtype, convert + rank + degree --------
    int nwords = 4 * E < 8192 ? 4 * E : 8192;
    k_detect_idx<<<dim3(1), blk, 0, stream>>>((const unsigned int*)ei, nwords, flag);
    hipMemsetAsync(deg, 0, (size_t)N * 4, stream);
    k_prep<<<dim3((E + 255) / 256), blk, 0, stream>>>(
        (const unsigned int*)ei, E, flag, idx32, rank, deg);

    // -------- scans + weight prep --------
    k_scan1<<<dim3(NB), blk, 0, stream>>>(deg, offs, bsum, N);
    k_scan2<<<dim3(1), blk, 0, stream>>>(bsum, NB);
    k_scan3<<<dim3(NB), blk, 0, stream>>>(offs, bsum, N, E);
    k_wprep<<<dim3((2 * 128 * 128 + 255) / 256), blk, 0, stream>>>(W1l, W1r, 128, 128, Wt1hi, Wt1lo);
    k_wprep<<<dim3((2 * 64 * 128 + 255) / 256), blk, 0, stream>>>(W2l, W2r, 128, 64, Wt2hi, Wt2lo);

    // -------- layer-1 GEMM co-scheduled with CSR scatter --------
    int gemmBlocks = (N + 127) / 128;
    int binBlocks = (E + 255) / 256;
    k_mfma_bin<128, 8, 128><<<dim3(gemmBlocks + binBlocks), blk, 0, stream>>>(
        x, Wt1hi, Wt1lo, xl, xr, N, gemmBlocks, idx32, rank, offs, csr, E);
    k_agg<7><<<dim3((N + 3) / 4), blk, 0, stream>>>(
        xl, xr, csr, offs, b1l, g1, be1, m1, v1, h, N);

    // -------- layer 2 --------
    k_mfma<128, 4, 64><<<dim3(gemmBlocks), blk, 0, stream>>>(h, Wt2hi, Wt2lo, t2l, t2r, N);
    k_agg<6><<<dim3((N + 3) / 4), blk, 0, stream>>>(
        t2l, t2r, csr, offs, b2l, g2, be2, m2, v2, h2, N);

    // -------- head --------
    k_head<<<dim3((N + 255) / 256), blk, 0, stream>>>(h2, Wh, bh, out, N);
}